// Round 6
// baseline (274.589 us; speedup 1.0000x reference)
//
#include <hip/hip_runtime.h>
#include <hip/hip_cooperative_groups.h>

namespace cg = cooperative_groups;

// Problem constants (match reference)
constexpr int Bn = 4, Dn = 128, Hn = 128, Wn = 128, Cn = 16;
constexpr int NPIX = Hn * Wn;  // 16384
constexpr int PS = 2;          // proto pixel-chunks per (b,d)
constexpr int CS = 8;          // count slices per batch (2048 px each)

// ws layout (floats), all plain stores, no zero-init, no atomics:
//   protoPart [Bn][PS][Cn][Dn] = 16384
//   countsPart[Bn][CS][Cn]     = 512
//   maskPart  [Bn][CS]         = 32
//   cePart    [1024]           = 1024

// ---------------------------------------------------------------------------
// Phase 1: per-(b,d,chunk) prototype partial sums (predicated cndmask).
// Blocks with d<4 also count labels (ballot/popc) + mask over slice
// s = chunk*4+d (2048 px) -> countsPart/maskPart. 1024 blocks, 256 thr.
// ---------------------------------------------------------------------------
__device__ void phase1(int bid,
                       const float* __restrict__ x,
                       const int* __restrict__ label,
                       const int* __restrict__ mask,
                       float* __restrict__ protoPart,
                       float* __restrict__ countsPart,
                       float* __restrict__ maskPart) {
    int chunk = bid & (PS - 1);
    int d = (bid >> 1) & (Dn - 1);
    int b = bid >> 8;               // 256 blocks per batch
    int tid = threadIdx.x;
    int wid = tid >> 6, lane = tid & 63;

    constexpr int CH = NPIX / PS;   // 8192 pixels per block
    const float4* xp = (const float4*)(x + (size_t)(b * Dn + d) * NPIX + chunk * CH);
    const int4*   lp = (const int4*)(label + (size_t)b * NPIX + chunk * CH);

    float acc[Cn];
#pragma unroll
    for (int c = 0; c < Cn; ++c) acc[c] = 0.f;

#pragma unroll 4
    for (int i = tid; i < CH / 4; i += 256) {   // 8 iterations
        float4 xv = xp[i];
        int4 lv = lp[i];
        int l0 = lv.x - 1, l1 = lv.y - 1, l2 = lv.z - 1, l3 = lv.w - 1;
#pragma unroll
        for (int c = 0; c < Cn; ++c) {
            acc[c] += ((l0 == c) ? xv.x : 0.f) + ((l1 == c) ? xv.y : 0.f)
                    + ((l2 == c) ? xv.z : 0.f) + ((l3 == c) ? xv.w : 0.f);
        }
    }

#pragma unroll
    for (int c = 0; c < Cn; ++c)
        for (int off = 32; off; off >>= 1) acc[c] += __shfl_down(acc[c], off);

    __shared__ float red[4][Cn];
    if (lane == 0) {
#pragma unroll
        for (int c = 0; c < Cn; ++c) red[wid][c] = acc[c];
    }
    __syncthreads();
    if (tid < Cn) {
        float s = red[0][tid] + red[1][tid] + red[2][tid] + red[3][tid];
        protoPart[(((size_t)b * PS + chunk) * Cn + tid) * Dn + d] = s;
    }

    if (d < 4) {   // block-uniform: counts + mask for slice s (2048 px)
        int s = chunk * 4 + d;
        const int4* lp2 = (const int4*)(label + (size_t)b * NPIX + s * 2048);
        const int4* mp2 = (const int4*)(mask  + (size_t)b * NPIX + s * 2048);
        int cnt[Cn];
#pragma unroll
        for (int c = 0; c < Cn; ++c) cnt[c] = 0;
        int msum = 0;
        for (int i = tid; i < 512; i += 256) {   // 2 iterations, uniform
            int4 lv = lp2[i];
            int4 mv = mp2[i];
            msum += mv.x + mv.y + mv.z + mv.w;
            int l0 = lv.x - 1, l1 = lv.y - 1, l2 = lv.z - 1, l3 = lv.w - 1;
#pragma unroll
            for (int c = 0; c < Cn; ++c) {
                cnt[c] += (int)__popcll(__ballot(l0 == c))
                        + (int)__popcll(__ballot(l1 == c))
                        + (int)__popcll(__ballot(l2 == c))
                        + (int)__popcll(__ballot(l3 == c));
            }
        }
        for (int off = 32; off; off >>= 1) msum += __shfl_down(msum, off);

        __shared__ int redi[4][Cn + 1];
        if (lane == 0) {
#pragma unroll
            for (int c = 0; c < Cn; ++c) redi[wid][c] = cnt[c];
            redi[wid][Cn] = msum;
        }
        __syncthreads();
        if (tid < Cn) {
            int t = redi[0][tid] + redi[1][tid] + redi[2][tid] + redi[3][tid];
            countsPart[((size_t)b * CS + s) * Cn + tid] = (float)t;
        } else if (tid == Cn) {
            int t = redi[0][Cn] + redi[1][Cn] + redi[2][Cn] + redi[3][Cn];
            maskPart[b * CS + s] = (float)t;
        }
    }
}

// ---------------------------------------------------------------------------
// Phase 3: metric + CE. Block covers 64 pixels; wave w handles d in
// [32w,32w+32). Proto finalized into LDS [d][c]; broadcast float4 reads.
// Per-block CE partial -> cePart[bid]. 1024 blocks, 256 thr.
// ---------------------------------------------------------------------------
__device__ void phase3(int bid,
                       const float* __restrict__ x,
                       const int* __restrict__ label,
                       const int* __restrict__ mask,
                       const float* __restrict__ protoPart,
                       const float* __restrict__ countsPart,
                       float* __restrict__ cePart) {
    int b = bid >> 8;                 // 256 blocks per batch
    int pbase = (bid & 255) << 6;     // 64 pixels per block
    int tid = threadIdx.x;
    int pix = tid & 63, dg = tid >> 6;

    __shared__ float cntInv[Cn];
    __shared__ float proto[Dn][Cn];   // 8 KB
    __shared__ float part[4][Cn][64]; // 16 KB

    if (tid < Cn) {
        float s = 0.f;
#pragma unroll
        for (int q = 0; q < CS; ++q)
            s += countsPart[((size_t)b * CS + q) * Cn + tid];
        cntInv[tid] = 1.f / s;
    }
    __syncthreads();
    for (int i = tid; i < Cn * Dn; i += 256) {
        int c = i >> 7;
        int d = i & (Dn - 1);
        float s = 0.f;
#pragma unroll
        for (int ch = 0; ch < PS; ++ch)
            s += protoPart[(((size_t)b * PS + ch) * Cn + c) * Dn + d];
        proto[d][c] = s * cntInv[c];
    }
    __syncthreads();

    float acc[Cn];
#pragma unroll
    for (int c = 0; c < Cn; ++c) acc[c] = 0.f;

    const float* xp = x + (size_t)b * Dn * NPIX + pbase + pix;
#pragma unroll 4
    for (int dd = 0; dd < 32; ++dd) {
        int d = (dg << 5) + dd;
        float xv = xp[(size_t)d * NPIX];
        float4 q0 = *(const float4*)&proto[d][0];
        float4 q1 = *(const float4*)&proto[d][4];
        float4 q2 = *(const float4*)&proto[d][8];
        float4 q3 = *(const float4*)&proto[d][12];
        acc[0]  += fabsf(xv - q0.x);  acc[1]  += fabsf(xv - q0.y);
        acc[2]  += fabsf(xv - q0.z);  acc[3]  += fabsf(xv - q0.w);
        acc[4]  += fabsf(xv - q1.x);  acc[5]  += fabsf(xv - q1.y);
        acc[6]  += fabsf(xv - q1.z);  acc[7]  += fabsf(xv - q1.w);
        acc[8]  += fabsf(xv - q2.x);  acc[9]  += fabsf(xv - q2.y);
        acc[10] += fabsf(xv - q2.z);  acc[11] += fabsf(xv - q2.w);
        acc[12] += fabsf(xv - q3.x);  acc[13] += fabsf(xv - q3.y);
        acc[14] += fabsf(xv - q3.z);  acc[15] += fabsf(xv - q3.w);
    }

#pragma unroll
    for (int c = 0; c < Cn; ++c) part[dg][c][pix] = acc[c];
    __syncthreads();

    if (tid < 64) {
        float a[Cn];
#pragma unroll
        for (int c = 0; c < Cn; ++c)
            a[c] = part[0][c][tid] + part[1][c][tid] + part[2][c][tid] + part[3][c][tid];

        float pd0[Cn];
        float mn = 3.4e38f;
#pragma unroll
        for (int c = 0; c < Cn; ++c) {
            pd0[c] = __expf(-a[c]);
            mn = fminf(mn, pd0[c]);
        }
        float se = 0.f;
#pragma unroll
        for (int c = 0; c < Cn; ++c) se += __expf(pd0[c] - mn);

        int p = pbase + tid;
        int l = label[b * NPIX + p] - 1;
        float pdl = 0.f;
#pragma unroll
        for (int c = 0; c < Cn; ++c) pdl = (l == c) ? (pd0[c] - mn) : pdl;

        float ce = __logf(se) - pdl;
        float m = (float)mask[b * NPIX + p];
        float v = ce * m;

        for (int off = 32; off; off >>= 1) v += __shfl_down(v, off);
        if (tid == 0) cePart[bid] = v;
    }
}

// ---------------------------------------------------------------------------
// Phase 4: final combine (one block). Thread t sums cePart[4t..4t+3]
// (all in batch t>>6 == wave id); wave reduce; divide by mask sum.
// ---------------------------------------------------------------------------
__device__ void phase4(const float* __restrict__ cePart,
                       const float* __restrict__ maskPart,
                       float* __restrict__ out) {
    int tid = threadIdx.x;
    int w = tid >> 6, lane = tid & 63;

    float s = cePart[4 * tid] + cePart[4 * tid + 1]
            + cePart[4 * tid + 2] + cePart[4 * tid + 3];
    for (int off = 32; off; off >>= 1) s += __shfl_down(s, off);

    __shared__ float r[4];
    if (lane == 0) {
        float ms = 0.f;
#pragma unroll
        for (int q = 0; q < CS; ++q) ms += maskPart[w * CS + q];
        r[w] = s / ms;
    }
    __syncthreads();
    if (tid == 0) out[0] = r[0] + r[1] + r[2] + r[3];
}

// ---------------------------------------------------------------------------
// Fused cooperative kernel: 1024 blocks x 256 threads, exactly co-resident
// at 4 blocks/CU (VGPR<=128 via launch_bounds; LDS ~24.8 KB).
// ---------------------------------------------------------------------------
__global__ __launch_bounds__(256, 4) void k_fused(
        const float* __restrict__ x,
        const int* __restrict__ label,
        const int* __restrict__ mask,
        float* __restrict__ protoPart,
        float* __restrict__ countsPart,
        float* __restrict__ maskPart,
        float* __restrict__ cePart,
        float* __restrict__ out) {
    cg::grid_group grid = cg::this_grid();
    int bid = blockIdx.x;

    phase1(bid, x, label, mask, protoPart, countsPart, maskPart);
    grid.sync();
    phase3(bid, x, label, mask, protoPart, countsPart, cePart);
    grid.sync();
    if (bid == 0) phase4(cePart, maskPart, out);
}

// Fallback path (classic 3-dispatch), same device functions.
__global__ __launch_bounds__(256) void k_p1(
        const float* __restrict__ x, const int* __restrict__ label,
        const int* __restrict__ mask, float* __restrict__ protoPart,
        float* __restrict__ countsPart, float* __restrict__ maskPart) {
    phase1(blockIdx.x, x, label, mask, protoPart, countsPart, maskPart);
}
__global__ __launch_bounds__(256) void k_p3(
        const float* __restrict__ x, const int* __restrict__ label,
        const int* __restrict__ mask, const float* __restrict__ protoPart,
        const float* __restrict__ countsPart, float* __restrict__ cePart) {
    phase3(blockIdx.x, x, label, mask, protoPart, countsPart, cePart);
}
__global__ void k_p4(const float* __restrict__ cePart,
                     const float* __restrict__ maskPart,
                     float* __restrict__ out) {
    phase4(cePart, maskPart, out);
}

extern "C" void kernel_launch(void* const* d_in, const int* in_sizes, int n_in,
                              void* d_out, int out_size, void* d_ws, size_t ws_size,
                              hipStream_t stream) {
    const float* x     = (const float*)d_in[0];  // [B,D,H,W] f32
    const int*   label = (const int*)d_in[1];    // [B,H,W]
    const int*   mask  = (const int*)d_in[2];    // [B,1,H,W]
    float* out = (float*)d_out;

    float* ws         = (float*)d_ws;
    float* protoPart  = ws;                               // 16384
    float* countsPart = protoPart + Bn * PS * Cn * Dn;    // 512
    float* maskPart   = countsPart + Bn * CS * Cn;        // 32
    float* cePart     = maskPart + Bn * CS;               // 1024

    void* args[] = {(void*)&x, (void*)&label, (void*)&mask,
                    (void*)&protoPart, (void*)&countsPart, (void*)&maskPart,
                    (void*)&cePart, (void*)&out};
    hipError_t err = hipLaunchCooperativeKernel((const void*)k_fused,
                                                dim3(1024), dim3(256),
                                                args, 0, stream);
    if (err != hipSuccess) {
        // Classic path: same math, 3 dispatches.
        k_p1<<<1024, 256, 0, stream>>>(x, label, mask,
                                       protoPart, countsPart, maskPart);
        k_p3<<<1024, 256, 0, stream>>>(x, label, mask,
                                       protoPart, countsPart, cePart);
        k_p4<<<1, 256, 0, stream>>>(cePart, maskPart, out);
    }
}

// Round 7
// 39.521 us; speedup vs baseline: 6.9478x; 6.9478x over previous
//
#include <hip/hip_runtime.h>

// Problem constants (match reference)
constexpr int Bn = 4, Dn = 128, Hn = 128, Wn = 128, Cn = 16;
constexpr int NPIX = Hn * Wn;  // 16384
constexpr int PS = 2;          // proto pixel-chunks per (b,d)
constexpr int CS = 8;          // count slices per batch (2048 px each)

// ws layout (floats), all plain stores, no zero-init, no atomics:
//   protoPart [Bn][PS][Dn][Cn] = 16384   (d-major, c-minor: coalesced both ends)
//   countsPart[Bn][CS][Cn]     = 512
//   maskPart  [Bn][CS]         = 32
//   cePart    [512]            = 512

// ---------------------------------------------------------------------------
// K1: per-(b,d,chunk) prototype partial sums (predicated cndmask accumulate,
// ~5 us VALU floor, ~5.3 us HBM floor). Blocks with d<4 also count labels
// (ballot/popc, SGPR-resident) + mask over slice s = chunk*4+d (2048 px).
// grid = Bn*Dn*PS = 1024 blocks, 256 threads -> 4 blocks/CU, 16 waves/CU.
// ---------------------------------------------------------------------------
__global__ __launch_bounds__(256) void k_proto(
        const float* __restrict__ x,
        const int* __restrict__ label,
        const int* __restrict__ mask,
        float* __restrict__ protoPart,   // [Bn][PS][Dn][Cn]
        float* __restrict__ countsPart,  // [Bn][CS][Cn]
        float* __restrict__ maskPart) {  // [Bn][CS]
    int bid = blockIdx.x;
    int chunk = bid & (PS - 1);
    int d = (bid >> 1) & (Dn - 1);
    int b = bid >> 8;               // 256 blocks per batch
    int tid = threadIdx.x;
    int wid = tid >> 6, lane = tid & 63;

    constexpr int CH = NPIX / PS;   // 8192 pixels per block
    const float4* xp = (const float4*)(x + (size_t)(b * Dn + d) * NPIX + chunk * CH);
    const int4*   lp = (const int4*)(label + (size_t)b * NPIX + chunk * CH);

    float acc[Cn];
#pragma unroll
    for (int c = 0; c < Cn; ++c) acc[c] = 0.f;

#pragma unroll 4
    for (int i = tid; i < CH / 4; i += 256) {   // 8 iterations
        float4 xv = xp[i];
        int4 lv = lp[i];
        int l0 = lv.x - 1, l1 = lv.y - 1, l2 = lv.z - 1, l3 = lv.w - 1;
#pragma unroll
        for (int c = 0; c < Cn; ++c) {
            acc[c] += ((l0 == c) ? xv.x : 0.f) + ((l1 == c) ? xv.y : 0.f)
                    + ((l2 == c) ? xv.z : 0.f) + ((l3 == c) ? xv.w : 0.f);
        }
    }

#pragma unroll
    for (int c = 0; c < Cn; ++c)
        for (int off = 32; off; off >>= 1) acc[c] += __shfl_down(acc[c], off);

    __shared__ float red[4][Cn];
    if (lane == 0) {
#pragma unroll
        for (int c = 0; c < Cn; ++c) red[wid][c] = acc[c];
    }
    __syncthreads();
    if (tid < Cn) {
        float s = red[0][tid] + red[1][tid] + red[2][tid] + red[3][tid];
        // [b][chunk][d][c]: 16 consecutive floats -> coalesced store
        protoPart[(((size_t)(b * PS + chunk)) * Dn + d) * Cn + tid] = s;
    }

    if (d < 4) {   // block-uniform: counts + mask for slice s (2048 px)
        int s = chunk * 4 + d;
        const int4* lp2 = (const int4*)(label + (size_t)b * NPIX + s * 2048);
        const int4* mp2 = (const int4*)(mask  + (size_t)b * NPIX + s * 2048);
        int cnt[Cn];
#pragma unroll
        for (int c = 0; c < Cn; ++c) cnt[c] = 0;
        int msum = 0;
        for (int i = tid; i < 512; i += 256) {   // 2 iterations
            int4 lv = lp2[i];
            int4 mv = mp2[i];
            msum += mv.x + mv.y + mv.z + mv.w;
            int l0 = lv.x - 1, l1 = lv.y - 1, l2 = lv.z - 1, l3 = lv.w - 1;
#pragma unroll
            for (int c = 0; c < Cn; ++c) {
                cnt[c] += (int)__popcll(__ballot(l0 == c))
                        + (int)__popcll(__ballot(l1 == c))
                        + (int)__popcll(__ballot(l2 == c))
                        + (int)__popcll(__ballot(l3 == c));
            }
        }
        for (int off = 32; off; off >>= 1) msum += __shfl_down(msum, off);

        __shared__ int redi[4][Cn + 1];
        if (lane == 0) {
#pragma unroll
            for (int c = 0; c < Cn; ++c) redi[wid][c] = cnt[c];
            redi[wid][Cn] = msum;
        }
        __syncthreads();
        if (tid < Cn) {
            int t = redi[0][tid] + redi[1][tid] + redi[2][tid] + redi[3][tid];
            countsPart[((size_t)b * CS + s) * Cn + tid] = (float)t;
        } else if (tid == Cn) {
            int t = redi[0][Cn] + redi[1][Cn] + redi[2][Cn] + redi[3][Cn];
            maskPart[b * CS + s] = (float)t;
        }
    }
}

// ---------------------------------------------------------------------------
// K2: metric + CE. Block = 256 threads covers 128 pixels (2 px/thread,
// float2 x loads); wave w handles d in [32w, 32w+32). Proto staged in LDS
// [d][c] (coalesced global read, conflict-free LDS write); the 32 KB
// partial-combine buffer ALIASES the proto buffer after a barrier, so
// total LDS = 32.1 KB -> 4 blocks/CU = 16 waves/CU.
// grid = Bn * (NPIX/128) = 512 blocks.
// ---------------------------------------------------------------------------
__global__ __launch_bounds__(256, 4) void k_main(
        const float* __restrict__ x,
        const int* __restrict__ label,
        const int* __restrict__ mask,
        const float* __restrict__ protoPart,  // [Bn][PS][Dn][Cn]
        const float* __restrict__ countsPart, // [Bn][CS][Cn]
        float* __restrict__ cePart) {         // [512]
    int b = blockIdx.x >> 7;                 // 128 blocks per batch
    int pbase = (blockIdx.x & 127) << 7;     // 128 pixels per block
    int tid = threadIdx.x;
    int lx = tid & 63, dg = tid >> 6;        // lane-x (pixel pair), d-group

    __shared__ float smem[4 * Cn * 128];     // 32 KB, aliased proto/part
    __shared__ float cntInv[Cn];
    __shared__ float r2[2];
    float (*proto)[Cn] = (float (*)[Cn])smem;          // [Dn][Cn]
    float (*part)[Cn][128] = (float (*)[Cn][128])smem; // [4][Cn][128]

    if (tid < Cn) {
        float s = 0.f;
#pragma unroll
        for (int q = 0; q < CS; ++q)
            s += countsPart[((size_t)b * CS + q) * Cn + tid];
        cntInv[tid] = 1.f / s;
    }
    __syncthreads();

    // stage proto: i -> (dd = i>>4, c = i&15); global reads coalesced,
    // LDS writes consecutive -> conflict-free.
    const float* pp0 = protoPart + ((size_t)(b * PS + 0)) * Dn * Cn;
    const float* pp1 = protoPart + ((size_t)(b * PS + 1)) * Dn * Cn;
    for (int i = tid; i < Dn * Cn; i += 256) {
        int c = i & (Cn - 1);
        smem[i] = (pp0[i] + pp1[i]) * cntInv[c];
    }
    __syncthreads();

    float2 acc[Cn];
#pragma unroll
    for (int c = 0; c < Cn; ++c) acc[c] = make_float2(0.f, 0.f);

    const float2* xp = (const float2*)(x + (size_t)b * Dn * NPIX + pbase) + lx;
#pragma unroll 2
    for (int dd = 0; dd < 32; ++dd) {
        int d = (dg << 5) + dd;
        float2 xv = xp[(size_t)d * (NPIX / 2)];
        float4 q0 = *(const float4*)&proto[d][0];
        float4 q1 = *(const float4*)&proto[d][4];
        float4 q2 = *(const float4*)&proto[d][8];
        float4 q3 = *(const float4*)&proto[d][12];
        acc[0].x  += fabsf(xv.x - q0.x);  acc[0].y  += fabsf(xv.y - q0.x);
        acc[1].x  += fabsf(xv.x - q0.y);  acc[1].y  += fabsf(xv.y - q0.y);
        acc[2].x  += fabsf(xv.x - q0.z);  acc[2].y  += fabsf(xv.y - q0.z);
        acc[3].x  += fabsf(xv.x - q0.w);  acc[3].y  += fabsf(xv.y - q0.w);
        acc[4].x  += fabsf(xv.x - q1.x);  acc[4].y  += fabsf(xv.y - q1.x);
        acc[5].x  += fabsf(xv.x - q1.y);  acc[5].y  += fabsf(xv.y - q1.y);
        acc[6].x  += fabsf(xv.x - q1.z);  acc[6].y  += fabsf(xv.y - q1.z);
        acc[7].x  += fabsf(xv.x - q1.w);  acc[7].y  += fabsf(xv.y - q1.w);
        acc[8].x  += fabsf(xv.x - q2.x);  acc[8].y  += fabsf(xv.y - q2.x);
        acc[9].x  += fabsf(xv.x - q2.y);  acc[9].y  += fabsf(xv.y - q2.y);
        acc[10].x += fabsf(xv.x - q2.z);  acc[10].y += fabsf(xv.y - q2.z);
        acc[11].x += fabsf(xv.x - q2.w);  acc[11].y += fabsf(xv.y - q2.w);
        acc[12].x += fabsf(xv.x - q3.x);  acc[12].y += fabsf(xv.y - q3.x);
        acc[13].x += fabsf(xv.x - q3.y);  acc[13].y += fabsf(xv.y - q3.y);
        acc[14].x += fabsf(xv.x - q3.z);  acc[14].y += fabsf(xv.y - q3.z);
        acc[15].x += fabsf(xv.x - q3.w);  acc[15].y += fabsf(xv.y - q3.w);
    }

    __syncthreads();   // all proto reads done -> smem reusable as part[]

#pragma unroll
    for (int c = 0; c < Cn; ++c)
        *(float2*)&part[dg][c][lx * 2] = acc[c];   // consecutive -> no conflict
    __syncthreads();

    float v = 0.f;
    if (tid < 128) {   // waves 0,1: epilogue for the 128 pixels
        float a[Cn];
#pragma unroll
        for (int c = 0; c < Cn; ++c)
            a[c] = part[0][c][tid] + part[1][c][tid]
                 + part[2][c][tid] + part[3][c][tid];

        float pd0[Cn];
        float mn = 3.4e38f;
#pragma unroll
        for (int c = 0; c < Cn; ++c) {
            pd0[c] = __expf(-a[c]);
            mn = fminf(mn, pd0[c]);
        }
        float se = 0.f;
#pragma unroll
        for (int c = 0; c < Cn; ++c) se += __expf(pd0[c] - mn);

        int p = pbase + tid;
        int l = label[b * NPIX + p] - 1;
        float pdl = 0.f;
#pragma unroll
        for (int c = 0; c < Cn; ++c) pdl = (l == c) ? (pd0[c] - mn) : pdl;

        float ce = __logf(se) - pdl;
        float m = (float)mask[b * NPIX + p];
        v = ce * m;

        for (int off = 32; off; off >>= 1) v += __shfl_down(v, off);
        if ((tid & 63) == 0) r2[tid >> 6] = v;
    }
    __syncthreads();
    if (tid == 0) cePart[blockIdx.x] = r2[0] + r2[1];
}

// ---------------------------------------------------------------------------
// K3: final combine. 1 block, 256 threads; wave w reduces batch w.
// ---------------------------------------------------------------------------
__global__ void k_final(const float* __restrict__ cePart,   // [Bn][128]
                        const float* __restrict__ maskPart, // [Bn][CS]
                        float* __restrict__ out) {
    int tid = threadIdx.x;
    int w = tid >> 6, lane = tid & 63;

    float s = cePart[w * 128 + lane] + cePart[w * 128 + lane + 64];
    for (int off = 32; off; off >>= 1) s += __shfl_down(s, off);

    __shared__ float r[4];
    if (lane == 0) {
        float ms = 0.f;
#pragma unroll
        for (int q = 0; q < CS; ++q) ms += maskPart[w * CS + q];
        r[w] = s / ms;
    }
    __syncthreads();
    if (tid == 0) out[0] = r[0] + r[1] + r[2] + r[3];
}

extern "C" void kernel_launch(void* const* d_in, const int* in_sizes, int n_in,
                              void* d_out, int out_size, void* d_ws, size_t ws_size,
                              hipStream_t stream) {
    const float* x     = (const float*)d_in[0];  // [B,D,H,W] f32
    const int*   label = (const int*)d_in[1];    // [B,H,W]
    const int*   mask  = (const int*)d_in[2];    // [B,1,H,W]
    float* out = (float*)d_out;

    float* ws         = (float*)d_ws;
    float* protoPart  = ws;                               // 16384
    float* countsPart = protoPart + Bn * PS * Dn * Cn;    // 512
    float* maskPart   = countsPart + Bn * CS * Cn;        // 32
    float* cePart     = maskPart + Bn * CS;               // 512

    k_proto<<<Bn * Dn * PS, 256, 0, stream>>>(x, label, mask,
                                              protoPart, countsPart, maskPart);
    k_main <<<Bn * (NPIX / 128), 256, 0, stream>>>(x, label, mask,
                                                   protoPart, countsPart, cePart);
    k_final<<<1, 256, 0, stream>>>(cePart, maskPart, out);
}